// Round 1
// baseline (246.578 us; speedup 1.0000x reference)
//
#include <hip/hip_runtime.h>
#include <hip/hip_bf16.h>

typedef __attribute__((ext_vector_type(8))) short bf16x8;
typedef __attribute__((ext_vector_type(4))) float f32x4;
typedef __attribute__((ext_vector_type(4))) float fvec4;
typedef __attribute__((ext_vector_type(8))) unsigned short u16x8;

// B=4, T=256, U=64 -> M = 65536 rows; K(J)=512; N(V)=1024

__device__ __forceinline__ unsigned short f2bf(float f) {
  unsigned int u = __builtin_bit_cast(unsigned int, f);
  u += 0x7FFFu + ((u >> 16) & 1u);   // round-to-nearest-even
  return (unsigned short)(u >> 16);
}

__device__ __forceinline__ float fast_tanh(float x) {
  float cx = fminf(fmaxf(x, -9.0f), 9.0f);
  float e2 = __expf(cx + cx);
  return (e2 - 1.0f) * __builtin_amdgcn_rcpf(e2 + 1.0f);
}

// out[row][j] = sum_k x[row][k] * W[k][j] + bias[j];  K=256, J=512, 8 rows/block
__global__ __launch_bounds__(256) void proj_kernel(
    const float* __restrict__ x, const float* __restrict__ W,
    const float* __restrict__ bias, float* __restrict__ out) {
  const int tid = threadIdx.x;
  const int row0 = blockIdx.x << 3;
  __shared__ float xt[256][9];   // [k][r], pad to 9 for conflict-free writes
  #pragma unroll
  for (int i = 0; i < 8; ++i) {
    // i -> row r=i, k=tid  (coalesced read)
    xt[tid][i] = x[(size_t)(row0 + i) * 256 + tid];
  }
  __syncthreads();
  float acc0[8] = {0.f,0.f,0.f,0.f,0.f,0.f,0.f,0.f};
  float acc1[8] = {0.f,0.f,0.f,0.f,0.f,0.f,0.f,0.f};
  #pragma unroll 2
  for (int k = 0; k < 256; ++k) {
    float w0 = W[(size_t)k * 512 + tid];
    float w1 = W[(size_t)k * 512 + tid + 256];
    #pragma unroll
    for (int r = 0; r < 8; ++r) {
      float xv = xt[k][r];
      acc0[r] = fmaf(xv, w0, acc0[r]);
      acc1[r] = fmaf(xv, w1, acc1[r]);
    }
  }
  float b0 = bias[tid], b1 = bias[tid + 256];
  #pragma unroll
  for (int r = 0; r < 8; ++r) {
    out[(size_t)(row0 + r) * 512 + tid]       = acc0[r] + b0;
    out[(size_t)(row0 + r) * 512 + tid + 256] = acc1[r] + b1;
  }
}

// Wt[n][k] = bf16(W[k][n]);  W: [512][1024] f32 -> Wt: [1024][512] bf16
__global__ __launch_bounds__(256) void wout_transpose(
    const float* __restrict__ W, unsigned short* __restrict__ Wt) {
  __shared__ unsigned short tile[64][65];
  const int k0 = (blockIdx.x & 7) << 6;    // 8 k-tiles
  const int n0 = (blockIdx.x >> 3) << 6;   // 16 n-tiles
  const int tid = threadIdx.x;
  #pragma unroll
  for (int i = 0; i < 16; ++i) {
    int idx = tid + (i << 8);
    int r = idx >> 6, c = idx & 63;        // r = k-off, c = n-off (coalesced read)
    tile[r][c] = f2bf(W[(size_t)(k0 + r) * 1024 + n0 + c]);
  }
  __syncthreads();
  #pragma unroll
  for (int i = 0; i < 16; ++i) {
    int idx = tid + (i << 8);
    int r = idx >> 6, c = idx & 63;        // r = n-off, c = k-off (coalesced write)
    Wt[(size_t)(n0 + r) * 512 + k0 + c] = tile[c][r];
  }
}

// A[m][k] = bf16(tanh(encp[m/U][k] + predp[(m/(T*U))*U + m%U][k])), 8 k per thread
__global__ __launch_bounds__(256) void joint_kernel(
    const float* __restrict__ encp, const float* __restrict__ predp,
    unsigned short* __restrict__ A) {
  int vid = blockIdx.x * 256 + threadIdx.x;   // 65536 * 64 units
  int m = vid >> 6;
  int k8 = (vid & 63) << 3;
  const float* e = encp + ((size_t)(m >> 6) << 9) + k8;
  const float* p = predp + ((size_t)(((m >> 14) << 6) | (m & 63)) << 9) + k8;
  fvec4 e0 = *(const fvec4*)e;
  fvec4 e1 = *(const fvec4*)(e + 4);
  fvec4 p0 = *(const fvec4*)p;
  fvec4 p1 = *(const fvec4*)(p + 4);
  u16x8 o;
  #pragma unroll
  for (int i = 0; i < 4; ++i) o[i]     = f2bf(fast_tanh(e0[i] + p0[i]));
  #pragma unroll
  for (int i = 0; i < 4; ++i) o[i + 4] = f2bf(fast_tanh(e1[i] + p1[i]));
  *(u16x8*)(A + ((size_t)m << 9) + k8) = o;
}

// C[m][n] = sum_k A[m][k]*Bt[n][k] + bout[n]
// 128x128 tile, BK=32, 4 waves (2x2), per-wave 64x64 via 4x4 mfma_f32_16x16x32_bf16
__global__ __launch_bounds__(256) void gemm_kernel(
    const unsigned short* __restrict__ A, const unsigned short* __restrict__ Bt,
    const float* __restrict__ bout, float* __restrict__ out) {
  __shared__ uint8_t smem[2][2][8192];   // [dbuf][A/B][128 rows x 32 bf16]
  const int b = blockIdx.x;
  const int wg = ((b & 7) << 9) + (b >> 3);   // XCD swizzle, 4096 % 8 == 0 (bijective)
  const int mt = wg >> 3, nt = wg & 7;
  const int m0 = mt << 7, n0 = nt << 7;
  const int tid = threadIdx.x;
  const int lane = tid & 63, wave = tid >> 6;
  const int wm = (wave >> 1) << 6, wn = (wave & 1) << 6;
  const int fr = lane & 15;   // row within 16x16 frag (M for A, N for B)
  const int fg = lane >> 4;   // k-group (8 bf16 each)

  f32x4 acc[4][4];
  f32x4 zero4 = {0.f, 0.f, 0.f, 0.f};
  #pragma unroll
  for (int i = 0; i < 4; ++i)
    #pragma unroll
    for (int j = 0; j < 4; ++j) acc[i][j] = zero4;

  auto stage = [&](int buf, int kt) {
    const unsigned short* gA = A + (size_t)m0 * 512 + (kt << 5);
    const unsigned short* gB = Bt + (size_t)n0 * 512 + (kt << 5);
    #pragma unroll
    for (int c = 0; c < 2; ++c) {
      int idx16 = (((c << 2) | wave) << 6) + lane;  // 16B chunk index 0..511
      int row = idx16 >> 2;                         // 4 chunks per 64B row
      int col8 = (idx16 & 3) << 3;
      __builtin_amdgcn_global_load_lds(
          (const __attribute__((address_space(1))) void*)(gA + (size_t)row * 512 + col8),
          (__attribute__((address_space(3))) void*)(&smem[buf][0][((c << 2) | wave) << 10]),
          16, 0, 0);
      __builtin_amdgcn_global_load_lds(
          (const __attribute__((address_space(1))) void*)(gB + (size_t)row * 512 + col8),
          (__attribute__((address_space(3))) void*)(&smem[buf][1][((c << 2) | wave) << 10]),
          16, 0, 0);
    }
  };

  stage(0, 0);
  int cur = 0;
  for (int kt = 0; kt < 16; ++kt) {
    __syncthreads();   // drains vmcnt(0): staged tile ready; prev compute done
    if (kt < 15) stage(cur ^ 1, kt + 1);
    const uint8_t* As = smem[cur][0];
    const uint8_t* Bs = smem[cur][1];
    bf16x8 af[4], bfv[4];
    #pragma unroll
    for (int mi = 0; mi < 4; ++mi)
      af[mi] = *(const bf16x8*)(As + ((wm + mi * 16 + fr) << 6) + (fg << 4));
    #pragma unroll
    for (int ni = 0; ni < 4; ++ni)
      bfv[ni] = *(const bf16x8*)(Bs + ((wn + ni * 16 + fr) << 6) + (fg << 4));
    #pragma unroll
    for (int mi = 0; mi < 4; ++mi)
      #pragma unroll
      for (int ni = 0; ni < 4; ++ni)
        acc[mi][ni] = __builtin_amdgcn_mfma_f32_16x16x32_bf16(af[mi], bfv[ni],
                                                              acc[mi][ni], 0, 0, 0);
    cur ^= 1;
  }

  // epilogue: C/D layout col = lane&15 (N), row = (lane>>4)*4 + reg (M)
  #pragma unroll
  for (int ni = 0; ni < 4; ++ni) {
    const int gn = n0 + wn + ni * 16 + fr;
    const float bv = bout[gn];
    #pragma unroll
    for (int mi = 0; mi < 4; ++mi) {
      const int gm = m0 + wm + mi * 16 + (fg << 2);
      #pragma unroll
      for (int r = 0; r < 4; ++r)
        out[(size_t)(gm + r) * 1024 + gn] = acc[mi][ni][r] + bv;
    }
  }
}

extern "C" void kernel_launch(void* const* d_in, const int* in_sizes, int n_in,
                              void* d_out, int out_size, void* d_ws, size_t ws_size,
                              hipStream_t stream) {
  const float* enc   = (const float*)d_in[0];
  const float* pred  = (const float*)d_in[1];
  const float* W_enc = (const float*)d_in[2];
  const float* b_enc = (const float*)d_in[3];
  const float* W_dec = (const float*)d_in[4];
  const float* b_dec = (const float*)d_in[5];
  const float* W_out = (const float*)d_in[6];
  const float* b_out = (const float*)d_in[7];
  float* out = (float*)d_out;

  uint8_t* ws = (uint8_t*)d_ws;
  float* encp  = (float*)ws;                           // [1024][512] f32, 2 MiB
  float* predp = (float*)(ws + 2097152);               // [256][512]  f32, 0.5 MiB
  unsigned short* wt = (unsigned short*)(ws + 2621440);// [1024][512] bf16, 1 MiB
  unsigned short* Aj = (unsigned short*)(ws + 3670016);// [65536][512] bf16, 64 MiB

  proj_kernel<<<128, 256, 0, stream>>>(enc, W_enc, b_enc, encp);   // 1024 rows
  proj_kernel<<<32, 256, 0, stream>>>(pred, W_dec, b_dec, predp);  // 256 rows
  wout_transpose<<<128, 256, 0, stream>>>(W_out, wt);
  joint_kernel<<<16384, 256, 0, stream>>>(encp, predp, Aj);
  gemm_kernel<<<4096, 256, 0, stream>>>(Aj, wt, b_out, out);
}

// Round 2
// 159.608 us; speedup vs baseline: 1.5449x; 1.5449x over previous
//
#include <hip/hip_runtime.h>
#include <hip/hip_bf16.h>

typedef __attribute__((ext_vector_type(8))) short bf16x8;
typedef __attribute__((ext_vector_type(4))) float f32x4;
typedef __attribute__((ext_vector_type(4))) float fvec4;
typedef __attribute__((ext_vector_type(8))) unsigned short u16x8;

// B=4, T=256, U=64 -> M = 65536 rows; K(J)=512; N(V)=1024

__device__ __forceinline__ unsigned short f2bf(float f) {
  unsigned int u = __builtin_bit_cast(unsigned int, f);
  u += 0x7FFFu + ((u >> 16) & 1u);   // round-to-nearest-even
  return (unsigned short)(u >> 16);
}

__device__ __forceinline__ float fast_tanh(float x) {
  float cx = fminf(fmaxf(x, -9.0f), 9.0f);
  float e2 = __expf(cx + cx);
  return (e2 - 1.0f) * __builtin_amdgcn_rcpf(e2 + 1.0f);
}

// ---- fused prep: enc-proj (blocks 0..127), pred-proj (128..159), W_out^T (160..287)

__device__ __forceinline__ void proj_body(
    const float* __restrict__ x, const float* __restrict__ W,
    const float* __restrict__ bias, float* __restrict__ out,
    int blk, uint8_t* sh) {
  float (*xt)[9] = (float (*)[9])sh;   // [256][9] f32 = 9216 B
  const int tid = threadIdx.x;
  const int row0 = blk << 3;
  #pragma unroll
  for (int i = 0; i < 8; ++i)
    xt[tid][i] = x[(size_t)(row0 + i) * 256 + tid];
  __syncthreads();
  float acc0[8] = {0.f,0.f,0.f,0.f,0.f,0.f,0.f,0.f};
  float acc1[8] = {0.f,0.f,0.f,0.f,0.f,0.f,0.f,0.f};
  #pragma unroll 4
  for (int k = 0; k < 256; ++k) {
    float w0 = W[(size_t)k * 512 + tid];
    float w1 = W[(size_t)k * 512 + tid + 256];
    #pragma unroll
    for (int r = 0; r < 8; ++r) {
      float xv = xt[k][r];
      acc0[r] = fmaf(xv, w0, acc0[r]);
      acc1[r] = fmaf(xv, w1, acc1[r]);
    }
  }
  float b0 = bias[tid], b1 = bias[tid + 256];
  #pragma unroll
  for (int r = 0; r < 8; ++r) {
    out[(size_t)(row0 + r) * 512 + tid]       = acc0[r] + b0;
    out[(size_t)(row0 + r) * 512 + tid + 256] = acc1[r] + b1;
  }
}

__device__ __forceinline__ void transpose_body(
    const float* __restrict__ W, unsigned short* __restrict__ Wt,
    int blk, uint8_t* sh) {
  unsigned short (*tile)[65] = (unsigned short (*)[65])sh;  // [64][65] = 8320 B
  const int k0 = (blk & 7) << 6;
  const int n0 = (blk >> 3) << 6;
  const int tid = threadIdx.x;
  #pragma unroll
  for (int i = 0; i < 16; ++i) {
    int idx = tid + (i << 8);
    int r = idx >> 6, c = idx & 63;
    tile[r][c] = f2bf(W[(size_t)(k0 + r) * 1024 + n0 + c]);
  }
  __syncthreads();
  #pragma unroll
  for (int i = 0; i < 16; ++i) {
    int idx = tid + (i << 8);
    int r = idx >> 6, c = idx & 63;
    Wt[(size_t)(n0 + r) * 512 + k0 + c] = tile[c][r];
  }
}

__global__ __launch_bounds__(256) void prep_kernel(
    const float* __restrict__ enc, const float* __restrict__ We,
    const float* __restrict__ be, float* __restrict__ encp,
    const float* __restrict__ pred, const float* __restrict__ Wd,
    const float* __restrict__ bd, float* __restrict__ predp,
    const float* __restrict__ Wo, unsigned short* __restrict__ Wt) {
  __shared__ uint8_t sh[9216];
  const int b = blockIdx.x;
  if (b < 128)       proj_body(enc, We, be, encp, b, sh);
  else if (b < 160)  proj_body(pred, Wd, bd, predp, b - 128, sh);
  else               transpose_body(Wo, Wt, b - 160, sh);
}

// ---- joint: A[m][k] = bf16(tanh(encp[m>>6][k] + predp[b*64 + (m&63)][k]))

__global__ __launch_bounds__(256) void joint_kernel(
    const float* __restrict__ encp, const float* __restrict__ predp,
    unsigned short* __restrict__ A) {
  int vid = blockIdx.x * 256 + threadIdx.x;   // 65536 rows * 64 chunks
  int m = vid >> 6;
  int k8 = (vid & 63) << 3;
  const float* e = encp + ((size_t)(m >> 6) << 9) + k8;
  const float* p = predp + ((size_t)(((m >> 14) << 6) | (m & 63)) << 9) + k8;
  fvec4 e0 = *(const fvec4*)e;
  fvec4 e1 = *(const fvec4*)(e + 4);
  fvec4 p0 = *(const fvec4*)p;
  fvec4 p1 = *(const fvec4*)(p + 4);
  u16x8 o;
  #pragma unroll
  for (int i = 0; i < 4; ++i) o[i]     = f2bf(fast_tanh(e0[i] + p0[i]));
  #pragma unroll
  for (int i = 0; i < 4; ++i) o[i + 4] = f2bf(fast_tanh(e1[i] + p1[i]));
  *(u16x8*)(A + ((size_t)m << 9) + k8) = o;
}

// ---- gemm: C[m][n] = sum_k A[m][k]*Bt[n][k] + bout[n]
// 128x128 tile, BK=32, 4 waves (2x2), per-wave 64x64 via 4x4 mfma_f32_16x16x32_bf16.
// MFMA operands SWAPPED (a<-B-frag, b<-A-frag): lane holds C[m=col][n=reg-dim]
// -> epilogue is 16x global_store_dwordx4 per thread (4 consecutive n per reg).
__global__ __launch_bounds__(256) void gemm_kernel(
    const unsigned short* __restrict__ A, const unsigned short* __restrict__ Bt,
    const float* __restrict__ bout, float* __restrict__ out) {
  __shared__ uint8_t smem[2][2][8192];   // [dbuf][A/B][128 rows x 32 bf16 (64B rows)]
  const int b = blockIdx.x;
  const int wg = ((b & 7) << 9) + (b >> 3);   // XCD swizzle, 4096 % 8 == 0 (bijective)
  const int mt = wg >> 3, nt = wg & 7;        // nt inner: 8 consecutive wg share A-panel
  const int m0 = mt << 7, n0 = nt << 7;
  const int tid = threadIdx.x;
  const int lane = tid & 63, wave = tid >> 6;
  const int wm = (wave >> 1) << 6, wn = (wave & 1) << 6;
  const int fr = lane & 15;   // fragment row (M for A-frags, N for B-frags)
  const int fg = lane >> 4;   // k-group (8 bf16 each)

  f32x4 acc[4][4];
  f32x4 zero4 = {0.f, 0.f, 0.f, 0.f};
  #pragma unroll
  for (int i = 0; i < 4; ++i)
    #pragma unroll
    for (int j = 0; j < 4; ++j) acc[i][j] = zero4;

  auto stage = [&](int buf, int kt) {
    const unsigned short* gA = A + (size_t)m0 * 512 + (kt << 5);
    const unsigned short* gB = Bt + (size_t)n0 * 512 + (kt << 5);
    #pragma unroll
    for (int c = 0; c < 2; ++c) {
      int idx16 = (((c << 2) | wave) << 6) + lane;  // 16B chunk index 0..511
      int row = idx16 >> 2;                         // 4 chunks per 64B row
      int col8 = (idx16 & 3) << 3;
      __builtin_amdgcn_global_load_lds(
          (const __attribute__((address_space(1))) void*)(gA + (size_t)row * 512 + col8),
          (__attribute__((address_space(3))) void*)(&smem[buf][0][((c << 2) | wave) << 10]),
          16, 0, 0);
      __builtin_amdgcn_global_load_lds(
          (const __attribute__((address_space(1))) void*)(gB + (size_t)row * 512 + col8),
          (__attribute__((address_space(3))) void*)(&smem[buf][1][((c << 2) | wave) << 10]),
          16, 0, 0);
    }
  };

  stage(0, 0);
  int cur = 0;
  for (int kt = 0; kt < 16; ++kt) {
    __syncthreads();   // drains vmcnt(0): staged tile ready; prev reads done
    if (kt < 15) stage(cur ^ 1, kt + 1);
    const uint8_t* As = smem[cur][0];
    const uint8_t* Bs = smem[cur][1];
    bf16x8 af[4], bfv[4];
    #pragma unroll
    for (int mi = 0; mi < 4; ++mi)
      af[mi] = *(const bf16x8*)(As + ((wm + mi * 16 + fr) << 6) + (fg << 4));
    #pragma unroll
    for (int ni = 0; ni < 4; ++ni)
      bfv[ni] = *(const bf16x8*)(Bs + ((wn + ni * 16 + fr) << 6) + (fg << 4));
    #pragma unroll
    for (int mi = 0; mi < 4; ++mi)
      #pragma unroll
      for (int ni = 0; ni < 4; ++ni)
        acc[mi][ni] = __builtin_amdgcn_mfma_f32_16x16x32_bf16(bfv[ni], af[mi],
                                                              acc[mi][ni], 0, 0, 0);
    cur ^= 1;
  }

  // epilogue: lane (fg,fr) holds C[m0+wm+mi*16+fr][n0+wn+ni*16+fg*4 + r], r=0..3
  #pragma unroll
  for (int ni = 0; ni < 4; ++ni) {
    const int gn = n0 + wn + ni * 16 + (fg << 2);
    const fvec4 bv = *(const fvec4*)&bout[gn];
    #pragma unroll
    for (int mi = 0; mi < 4; ++mi) {
      const int gm = m0 + wm + mi * 16 + fr;
      fvec4 o = acc[mi][ni] + bv;
      *(fvec4*)&out[(size_t)gm * 1024 + gn] = o;
    }
  }
}

extern "C" void kernel_launch(void* const* d_in, const int* in_sizes, int n_in,
                              void* d_out, int out_size, void* d_ws, size_t ws_size,
                              hipStream_t stream) {
  const float* enc   = (const float*)d_in[0];
  const float* pred  = (const float*)d_in[1];
  const float* W_enc = (const float*)d_in[2];
  const float* b_enc = (const float*)d_in[3];
  const float* W_dec = (const float*)d_in[4];
  const float* b_dec = (const float*)d_in[5];
  const float* W_out = (const float*)d_in[6];
  const float* b_out = (const float*)d_in[7];
  float* out = (float*)d_out;

  uint8_t* ws = (uint8_t*)d_ws;
  float* encp  = (float*)ws;                           // [1024][512] f32, 2 MiB
  float* predp = (float*)(ws + 2097152);               // [256][512]  f32, 0.5 MiB
  unsigned short* wt = (unsigned short*)(ws + 2621440);// [1024][512] bf16, 1 MiB
  unsigned short* Aj = (unsigned short*)(ws + 3670016);// [65536][512] bf16, 64 MiB

  prep_kernel<<<288, 256, 0, stream>>>(enc, W_enc, b_enc, encp,
                                       pred, W_dec, b_dec, predp,
                                       W_out, wt);
  joint_kernel<<<16384, 256, 0, stream>>>(encp, predp, Aj);
  gemm_kernel<<<4096, 256, 0, stream>>>(Aj, wt, b_out, out);
}